// Round 9
// baseline (4796.677 us; speedup 1.0000x reference)
//
#include <hip/hip_runtime.h>
#include <stdint.h>

#define B_ 64
#define T_ 512
#define D_ 1024
#define U_ 1024
#define G4_ 4096
#define M_ (B_ * T_)  // 32768

typedef unsigned short u16;
typedef float f32x4 __attribute__((ext_vector_type(4)));
typedef _Float16 f16x8 __attribute__((ext_vector_type(8)));
typedef unsigned short u16x4 __attribute__((ext_vector_type(4)));

__device__ __forceinline__ u16 f2h(float f) {
  union { _Float16 h; u16 u; } v; v.h = (_Float16)f; return v.u;
}
__device__ __forceinline__ float h2f(uint32_t u) {
  union { _Float16 h; u16 u; } v; v.u = (u16)u; return (float)v.h;
}
__device__ __forceinline__ float sigm(float x) { return 1.f / (1.f + __expf(-x)); }
__device__ __forceinline__ float tanhf_(float x) {
  x = fminf(12.f, fmaxf(-12.f, x));
  float e = __expf(2.f * x);
  return (e - 1.f) / (e + 1.f);
}

__device__ __forceinline__ void glds16(const void* g, void* l) {
  __builtin_amdgcn_global_load_lds(
      (const __attribute__((address_space(1))) uint32_t*)g,
      (__attribute__((address_space(3))) uint32_t*)l, 16, 0, 0);
}

template <int R>
__device__ __forceinline__ void stage_tile(const char* gbase, long gs, char* lds, int tid) {
  const int lane = tid & 63, wid = tid >> 6;
#pragma unroll
  for (int j = wid; j < R / 8; j += 4) {
    const int row = j * 8 + (lane >> 3);
    const int lg = ((lane & 7) * 16) ^ ((row & 7) << 4);
    glds16(gbase + (long)row * gs + lg, lds + j * 1024);
  }
}

__device__ __forceinline__ f16x8 read_frag(const char* lds, int row, int kbyte) {
  const int ph = row * 128 + (kbyte ^ ((row & 7) << 4));
  return *(const f16x8*)(lds + ph);
}

#define MFMA_(a, b, c) __builtin_amdgcn_mfma_f32_16x16x32_f16(a, b, c, 0, 0, 0)
#define BAR_LGKM() asm volatile("s_waitcnt lgkmcnt(0)\n\ts_barrier" ::: "memory")

// ---------------- prep kernels ----------------

__global__ __launch_bounds__(256) void cast_x_kernel(const float* __restrict__ x,
                                                     u16* __restrict__ xb) {
  const long n = (long)M_ * D_ / 4;
  for (long i = (long)blockIdx.x * blockDim.x + threadIdx.x; i < n;
       i += (long)gridDim.x * blockDim.x) {
    f32x4 v = ((const f32x4*)x)[i];
    u16x4 r;
#pragma unroll
    for (int j = 0; j < 4; ++j) { union { _Float16 h; u16 u; } c; c.h = (_Float16)v[j]; r[j] = c.u; }
    ((u16x4*)xb)[i] = r;
  }
}

__global__ __launch_bounds__(256) void pack_w_kernel(const float* __restrict__ Wf,
                                                     const float* __restrict__ Wb,
                                                     u16* __restrict__ wxT,
                                                     u16* __restrict__ whT) {
  const int idx = blockIdx.x * 256 + threadIdx.x;
  const int p = idx & 4095;
  const int kc = (idx >> 12) & 63;
  const int part = (idx >> 18) & 1;
  const int d = (idx >> 19) & 1;
  const float* W = d ? Wb : Wf;
  const int orig = ((p >> 4) & 3) * 1024 + ((p >> 6) << 4) + (p & 15);
  u16* dst = (part ? whT : wxT) + ((long)d * G4_ + p) * 1024 + kc * 16;
  const float* src = W + ((long)(part * 1024 + kc * 16)) * G4_ + orig;
#pragma unroll
  for (int j = 0; j < 16; ++j) dst[j] = f2h(src[(long)j * G4_]);
}

// ---------------- big x-projection GEMM (128x128 tile) ----------------
__global__ __launch_bounds__(256) void gemm_xproj2(const u16* __restrict__ xbf,
                                                   const u16* __restrict__ wT,
                                                   const float* __restrict__ bF,
                                                   const float* __restrict__ bB,
                                                   u16* __restrict__ xp2) {
  __shared__ __align__(16) char smem[64 * 1024];
  const int tid = threadIdx.x, lane = tid & 63, wid = tid >> 6;
  const int wr = wid >> 1, wc = wid & 1;
  const int tm = blockIdx.x * 128, tn = blockIdx.y * 128, d = blockIdx.z;
  const char* Ag = (const char*)xbf + (long)tm * 2048;
  const char* Bg = (const char*)wT + ((long)d * G4_ + tn) * 2048;

  f32x4 acc[4][4];
#pragma unroll
  for (int mi = 0; mi < 4; ++mi)
#pragma unroll
    for (int ni = 0; ni < 4; ++ni)
#pragma unroll
      for (int v = 0; v < 4; ++v) acc[mi][ni][v] = 0.f;

  stage_tile<128>(Ag, 2048, smem, tid);
  stage_tile<128>(Bg, 2048, smem + 32768, tid);
  __syncthreads();
  const int rA = lane & 15, kb = (lane >> 4) * 16;

  for (int cc = 0; cc < 16; ++cc) {
    const int cur = cc & 1;
    char* Ac = smem + cur * 16384;
    char* Bc = smem + 32768 + cur * 16384;
    if (cc + 1 < 16) {
      stage_tile<128>(Ag + (cc + 1) * 128, 2048, smem + (cur ^ 1) * 16384, tid);
      stage_tile<128>(Bg + (cc + 1) * 128, 2048, smem + 32768 + (cur ^ 1) * 16384, tid);
    }
    f16x8 aF[4][2], bFr[4][2];
#pragma unroll
    for (int mi = 0; mi < 4; ++mi)
#pragma unroll
      for (int ks = 0; ks < 2; ++ks)
        aF[mi][ks] = read_frag(Ac, wr * 64 + mi * 16 + rA, kb + ks * 64);
#pragma unroll
    for (int ni = 0; ni < 4; ++ni)
#pragma unroll
      for (int ks = 0; ks < 2; ++ks)
        bFr[ni][ks] = read_frag(Bc, wc * 64 + ni * 16 + rA, kb + ks * 64);
#pragma unroll
    for (int mi = 0; mi < 4; ++mi)
#pragma unroll
      for (int ni = 0; ni < 4; ++ni)
#pragma unroll
        for (int ks = 0; ks < 2; ++ks)
          acc[mi][ni] = MFMA_(aF[mi][ks], bFr[ni][ks], acc[mi][ni]);
    __syncthreads();
  }

  const float* bias = d ? bB : bF;
#pragma unroll
  for (int ni = 0; ni < 4; ++ni) {
    const int p = tn + wc * 64 + ni * 16 + rA;
    const int orig = ((p >> 4) & 3) * 1024 + ((p >> 6) << 4) + (p & 15);
    const float bv = bias[orig];
    const int ub2 = p >> 6, pl = p & 63;
#pragma unroll
    for (int mi = 0; mi < 4; ++mi) {
      const int m0 = tm + wr * 64 + mi * 16 + (lane >> 4) * 4;
#pragma unroll
      for (int v = 0; v < 4; ++v) {
        const int m = m0 + v, b = m >> 9, t = m & 511;
        xp2[((((long)d * T_ + t) * 64 + ub2) * 64 + b) * 64 + pl] =
            f2h(acc[mi][ni][v] + bv);
      }
    }
  }
}

// ---------------- persistent recurrent kernel v5 ----------------
// 128 blocks (d, ub), 512 threads, 8 waves = 4 M x 2 K-halves.
// Protocol v5: K-half decoupled start (wave0/wave4 poll their half's 32 flags,
// relay via LDS token); gates fully in-register on kh0 waves (fragment layout:
// lane rA = unit, ni = gate, v = batch row); kh1 = pure compute (no stores).
// Only 2 all-wave barriers/step (B2 half-sum, B2b WAR). Flag release via LDS
// counter over the 4 kh0 waves only. Tight polls, capped (bailout, no hang).
#define ZLD 65
__global__ __launch_bounds__(512) void lstm_persist(
    const u16* __restrict__ whT, const u16* __restrict__ xp2,
    u16* __restrict__ hst, float* __restrict__ out, uint32_t* flags) {
  __shared__ __align__(16) char smem[131072 + ZLD * 64 * 4 + 16];
  float* zbuf = (float*)(smem + 131072);
  int* tok = (int*)(smem + 131072 + ZLD * 64 * 4);  // [tok0, tok1, cnt, pad]
  const int tid = threadIdx.x, lane = tid & 63, wid = tid >> 6;
  const int bx = blockIdx.x, d = bx & 1, ub = bx >> 1;
  const int wm = wid & 3, kh = wid >> 2, rA = lane & 15, kq = lane >> 4;

  if (tid == 0) { tok[0] = -1; tok[1] = -1; tok[2] = 0; }

  // ---- stage W once, fragment-linear (conflict-free B reads) ----
  {
    const char* wbase = (const char*)(whT + ((long)d * G4_ + ub * 64) * 1024);
#pragma unroll
    for (int q = 0; q < 16; ++q) {
      const int f = wid * 16 + q;
      const int ni = f >> 5, kkg = f & 31;
      const int row = ni * 16 + (lane & 15);
      glds16(wbase + (long)row * 2048 + kkg * 64 + (lane >> 4) * 16,
             smem + f * 1024);
    }
  }
  asm volatile("s_waitcnt vmcnt(0)" ::: "memory");
  __syncthreads();

  const int u_g = ub * 16 + rA;        // this lane's unit (kh0 gate duty)
  const int row0 = wm * 16 + kq * 4;   // first of 4 batch rows
  f32x4 creg;
#pragma unroll
  for (int v = 0; v < 4; ++v) creg[v] = 0.f;
  uint32_t* fl = flags + (long)d * 64 * 4;  // 16B-padded slots

  for (int s = 0; s < T_; ++s) {
    const int t = d ? (T_ - 1 - s) : s;

    // ---- xp prefetch (kh0 only, gate-fragment layout), before the wait ----
    uint32_t xr[4][4];
    if (kh == 0) {
      const char* xpb = (const char*)(xp2 + (((long)d * T_ + t) * 64 + ub) * 4096);
#pragma unroll
      for (int v = 0; v < 4; ++v) {
        const char* bp = xpb + ((row0 + v) * 64 + rA) * 2;
#define XL(g)                                                            \
  asm volatile("global_load_ushort %0, %1, off offset:%2"                \
               : "=v"(xr[v][g]) : "v"(bp), "n"(g * 32) : "memory")
        XL(0); XL(1); XL(2); XL(3);
#undef XL
      }
    }

    // ---- half-barrier: wave0 polls lower 32 flags, wave4 upper 32 ----
    if (wid == 0 || wid == 4) {
      const uint32_t* fp = fl + ((lane & 31) + kh * 32) * 4;
      int it = 0;
      while (true) {
        uint32_t v;
        asm volatile("global_load_dword %0, %1, off sc0 sc1\n\ts_waitcnt vmcnt(0)"
                     : "=v"(v) : "v"(fp) : "memory");
        if (__all(v >= (uint32_t)s)) break;
        if (++it > (1 << 17)) break;  // bailout
      }
      __hip_atomic_store(tok + kh, s, __ATOMIC_RELAXED, __HIP_MEMORY_SCOPE_WORKGROUP);
    }
    {
      int it = 0;
      while (__hip_atomic_load(tok + kh, __ATOMIC_RELAXED,
                               __HIP_MEMORY_SCOPE_WORKGROUP) < s) {
        if (++it > (1 << 20)) break;  // bailout
      }
    }

    // ---- A-loads (own K-half, LLC-direct), one wait ----
    const u16* hr = hst + (long)(s & 1) * 131072 + d * 65536;
    const char* abase =
        (const char*)(hr + ((long)(wm * 16 + rA)) * 1024) + kh * 1024 + kq * 16;
    f16x8 areg[16];
#define ALOAD(i)                                                        \
  asm volatile("global_load_dwordx4 %0, %1, off offset:%2 sc0 sc1"     \
               : "=v"(areg[i]) : "v"(abase), "n"(i * 64) : "memory")
    ALOAD(0); ALOAD(1); ALOAD(2); ALOAD(3);
    ALOAD(4); ALOAD(5); ALOAD(6); ALOAD(7);
    ALOAD(8); ALOAD(9); ALOAD(10); ALOAD(11);
    ALOAD(12); ALOAD(13); ALOAD(14); ALOAD(15);
#undef ALOAD
    asm volatile("s_waitcnt vmcnt(0)" ::: "memory");
    __builtin_amdgcn_sched_barrier(0);  // rule #18

    // ---- MFMA burst (fragment-linear B, conflict-free) ----
    f32x4 acc[4];
#pragma unroll
    for (int ni = 0; ni < 4; ++ni)
#pragma unroll
      for (int v = 0; v < 4; ++v) acc[ni][v] = 0.f;
    const char* bbase = smem + (kh << 14) + (lane << 4);
#pragma unroll
    for (int kk = 0; kk < 16; ++kk) {
#pragma unroll
      for (int ni = 0; ni < 4; ++ni) {
        const f16x8 bF = *(const f16x8*)(bbase + (ni << 15) + (kk << 10));
        acc[ni] = MFMA_(areg[kk], bF, acc[ni]);
      }
    }

    // ---- half-sum: kh1 -> zbuf; kh0 combines in-register after B2 ----
    if (kh == 1) {
#pragma unroll
      for (int ni = 0; ni < 4; ++ni)
#pragma unroll
        for (int v = 0; v < 4; ++v)
          zbuf[(row0 + v) * ZLD + ni * 16 + rA] = acc[ni][v];
    }
    BAR_LGKM();  // B2
    if (kh == 0) {
#pragma unroll
      for (int ni = 0; ni < 4; ++ni)
#pragma unroll
        for (int v = 0; v < 4; ++v)
          acc[ni][v] += zbuf[(row0 + v) * ZLD + ni * 16 + rA];
    }
    BAR_LGKM();  // B2b (WAR: zbuf free for next step)

    if (kh == 0) {
      // ---- gates in-register: ni = gate (i,f,o,g), v = batch row ----
      float hn[4];
#pragma unroll
      for (int v = 0; v < 4; ++v) {
        const float zi = acc[0][v] + h2f(xr[v][0]);
        const float zf = acc[1][v] + h2f(xr[v][1]);
        const float zo = acc[2][v] + h2f(xr[v][2]);
        const float zg = acc[3][v] + h2f(xr[v][3]);
        const float cn = sigm(zf) * creg[v] + sigm(zi) * tanhf_(zg);
        hn[v] = sigm(zo) * tanhf_(cn);
        creg[v] = cn;
      }
      // ---- h stores (write-through) -> ack -> kh0 counter -> flag ----
      u16* hw = hst + (long)((s + 1) & 1) * 131072 + d * 65536;
#pragma unroll
      for (int v = 0; v < 4; ++v) {
        union { _Float16 h; u16 u; } cv; cv.h = (_Float16)hn[v];
        const uint32_t hv = cv.u;
        u16* hp = hw + (long)(row0 + v) * 1024 + u_g;
        asm volatile("global_store_short %0, %1, off sc0 sc1"
                     :: "v"(hp), "v"(hv) : "memory");
      }
      asm volatile("s_waitcnt vmcnt(0)" ::: "memory");
      if (lane == 0)
        __hip_atomic_fetch_add(tok + 2, 1, __ATOMIC_RELAXED,
                               __HIP_MEMORY_SCOPE_WORKGROUP);
      if (tid == 0) {
        int it = 0;
        while (__hip_atomic_load(tok + 2, __ATOMIC_RELAXED,
                                 __HIP_MEMORY_SCOPE_WORKGROUP) < 4 * (s + 1)) {
          if (++it > (1 << 20)) break;  // bailout
        }
        const uint32_t fv = (uint32_t)(s + 1);
        uint32_t* fp2 = fl + ub * 4;
        asm volatile("global_store_dword %0, %1, off sc0 sc1"
                     :: "v"(fp2), "v"(fv) : "memory");
      }
      // ---- out stores AFTER release ----
#pragma unroll
      for (int v = 0; v < 4; ++v)
        out[((long)(row0 + v) * T_ + t) * 2048 + d * 1024 + u_g] = hn[v];
    }
  }
}

// ---------------- fused fallback (small workspace): r3-proven structure ------
__global__ __launch_bounds__(256) void lstm_step_fused(
    const u16* __restrict__ whT, const u16* __restrict__ wxT,
    const u16* __restrict__ xbf,
    const float* __restrict__ bF, const float* __restrict__ bB,
    const u16* __restrict__ h_read, u16* __restrict__ h_write,
    float* __restrict__ c_state, float* __restrict__ out, int s) {
  __shared__ __align__(16) char smem[32 * 1024];
  float* zbuf = (float*)smem;
  const int tid = threadIdx.x, lane = tid & 63, wid = tid >> 6;
  const int wr = wid >> 1, wc = wid & 1;
  const int ub = blockIdx.x, d = blockIdx.y;
  const int t = d ? (T_ - 1 - s) : s;
  const char* hA = (const char*)(h_read + (long)d * B_ * U_);
  const char* Bh = (const char*)(whT + ((long)d * G4_ + ub * 64) * 1024);
  const char* xA = (const char*)xbf + (long)t * (D_ * 2);
  const char* Bx = (const char*)(wxT + ((long)d * G4_ + ub * 64) * 1024);

  auto stage = [&](int cc, int buf) {
    char* Ad = smem + buf * 8192;
    char* Bd = smem + 16384 + buf * 8192;
    if (cc < 16) {
      stage_tile<64>(hA + cc * 128, U_ * 2, Ad, tid);
      stage_tile<64>(Bh + cc * 128, 1024 * 2, Bd, tid);
    } else {
      const int cx = cc - 16;
      stage_tile<64>(xA + cx * 128, (long)T_ * D_ * 2, Ad, tid);
      stage_tile<64>(Bx + cx * 128, 1024 * 2, Bd, tid);
    }
  };

  f32x4 acc[2][2];
#pragma unroll
  for (int mi = 0; mi < 2; ++mi)
#pragma unroll
    for (int ni = 0; ni < 2; ++ni)
#pragma unroll
      for (int v = 0; v < 4; ++v) acc[mi][ni][v] = 0.f;

  stage(0, 0);
  __syncthreads();
  const int rA = lane & 15, kb = (lane >> 4) * 16;

  for (int cc = 0; cc < 32; ++cc) {
    const int cur = cc & 1;
    char* Ac = smem + cur * 8192;
    char* Bc = smem + 16384 + cur * 8192;
    if (cc + 1 < 32) stage(cc + 1, cur ^ 1);
    f16x8 aF[2][2], bFr[2][2];
#pragma unroll
    for (int mi = 0; mi < 2; ++mi)
#pragma unroll
      for (int ks = 0; ks < 2; ++ks)
        aF[mi][ks] = read_frag(Ac, wr * 32 + mi * 16 + rA, kb + ks * 64);
#pragma unroll
    for (int ni = 0; ni < 2; ++ni)
#pragma unroll
      for (int ks = 0; ks < 2; ++ks)
        bFr[ni][ks] = read_frag(Bc, wc * 32 + ni * 16 + rA, kb + ks * 64);
#pragma unroll
    for (int mi = 0; mi < 2; ++mi)
#pragma unroll
      for (int ni = 0; ni < 2; ++ni)
#pragma unroll
        for (int ks = 0; ks < 2; ++ks)
          acc[mi][ni] = MFMA_(aF[mi][ks], bFr[ni][ks], acc[mi][ni]);
    __syncthreads();
  }

#pragma unroll
  for (int mi = 0; mi < 2; ++mi)
#pragma unroll
    for (int ni = 0; ni < 2; ++ni)
#pragma unroll
      for (int v = 0; v < 4; ++v) {
        const int row = wr * 32 + mi * 16 + (lane >> 4) * 4 + v;
        const int col = wc * 32 + ni * 16 + rA;
        zbuf[row * 64 + col] = acc[mi][ni][v];
      }
  __syncthreads();

  const int b = tid >> 2, u0 = (tid & 3) * 4;
  const float* bias = d ? bB : bF;
#pragma unroll
  for (int j = 0; j < 4; ++j) {
    const int ui = u0 + j, u = ub * 16 + ui;
    float zi = zbuf[b * 64 + ui] + bias[u];
    float zf = zbuf[b * 64 + 16 + ui] + bias[1024 + u];
    float zo = zbuf[b * 64 + 32 + ui] + bias[2048 + u];
    float zg = zbuf[b * 64 + 48 + ui] + bias[3072 + u];
    const long ci = (((long)d * B_ + b) << 10) + u;
    const float c = c_state[ci];
    const float i_ = sigm(zi), ff = sigm(zf), o_ = sigm(zo), g_ = tanhf_(zg);
    const float cn = ff * c + i_ * g_;
    const float hn = o_ * tanhf_(cn);
    c_state[ci] = cn;
    h_write[ci] = f2h(hn);
    out[(((long)b * T_ + t) << 11) + ((long)d << 10) + u] = hn;
  }
}

// ---------------- host launch ----------------

extern "C" void kernel_launch(void* const* d_in, const int* in_sizes, int n_in,
                              void* d_out, int out_size, void* d_ws, size_t ws_size,
                              hipStream_t stream) {
  const float* x = (const float*)d_in[0];
  const float* Wf = (const float*)d_in[1];
  const float* bfp = (const float*)d_in[2];
  const float* Wb = (const float*)d_in[3];
  const float* bbp = (const float*)d_in[4];
  float* out = (float*)d_out;
  char* ws = (char*)d_ws;

  size_t off = 0;
  auto alloc = [&](size_t bytes) {
    char* p = ws + off;
    off = (off + bytes + 255) & ~(size_t)255;
    return p;
  };
  u16* xbf = (u16*)alloc((size_t)M_ * D_ * 2);            // 64 MB
  u16* wxT = (u16*)alloc((size_t)2 * G4_ * 1024 * 2);     // 16 MB
  u16* whT = (u16*)alloc((size_t)2 * G4_ * 1024 * 2);     // 16 MB
  u16* hst = (u16*)alloc((size_t)2 * 2 * B_ * U_ * 2);    // ping-pong h
  float* cst = (float*)alloc((size_t)2 * B_ * U_ * 4);    // cell state (fallback)
  uint32_t* flags = (uint32_t*)alloc((size_t)2 * 64 * 16 * 4);
  const size_t base_need = off;
  const size_t xproj_bytes = (size_t)2 * B_ * T_ * G4_ * 2;  // 512 MB
  const bool fused = (ws_size < base_need + xproj_bytes + 256);
  u16* xproj = fused ? nullptr : (u16*)alloc(xproj_bytes);

  hipMemsetAsync(hst, 0, (size_t)2 * 2 * B_ * U_ * 2, stream);
  hipMemsetAsync(flags, 0, (size_t)2 * 64 * 16 * 4, stream);

  cast_x_kernel<<<2048, 256, 0, stream>>>(x, xbf);
  pack_w_kernel<<<4096, 256, 0, stream>>>(Wf, Wb, wxT, whT);

  if (!fused) {
    dim3 gg(M_ / 128, G4_ / 128, 2);
    gemm_xproj2<<<gg, 256, 0, stream>>>(xbf, wxT, bfp, bbp, xproj);
    lstm_persist<<<128, 512, 0, stream>>>(whT, xproj, hst, out, flags);
  } else {
    hipMemsetAsync(cst, 0, (size_t)2 * B_ * U_ * 4, stream);
    for (int s = 0; s < T_; ++s) {
      const u16* hr = hst + (size_t)(s & 1) * 2 * B_ * U_;
      u16* hw = hst + (size_t)((s + 1) & 1) * 2 * B_ * U_;
      lstm_step_fused<<<dim3(64, 2), 256, 0, stream>>>(whT, wxT, xbf, bfp, bbp,
                                                       hr, hw, cst, out, s);
    }
  }
}